// Round 1
// baseline (3715.556 us; speedup 1.0000x reference)
//
#include <hip/hip_runtime.h>
#include <math.h>

#define BATCH 512
#define SEQL  100
#define DIM   128
#define NITEMS 100000
#define NEGV  -1000000000.0f

// ---- workspace layout (float offsets) ----
#define OFF_WIHT   0         // 128x384  [k*384+j]
#define OFF_WHHT   49152
#define OFF_WINT   98304     // 128x128  [k*128+j]
#define OFF_WOUTT  114688
#define OFF_WREADT 131072    // 384x128  [j*128+i]
#define OFF_HREAD  180224    // 512x128
#define OFF_DEG    245760    // 512x100
#define OFF_XIN    296960    // 51200x128
#define OFF_HOUT   6850560   // 51200x128 (later holds H)
// ---- int offsets (in ints from ws base) ----
#define OFF_NODES_I 13404160 // 512x100 tokens (padded with 0)
#define OFF_SRC_I   13455360 // 512x99
#define OFF_DST_I   13506048 // 512x99
#define OFF_INFO_I  13556736 // 512x4: ecnt, li, flag(cnt>=2), n_nodes

// ------------------------------------------------------------------
// K0: transpose weights into ws
__global__ void k_prep(const float* __restrict__ w_ih, const float* __restrict__ w_hh,
                       const float* __restrict__ W_in, const float* __restrict__ W_out,
                       const float* __restrict__ W_read, float* __restrict__ ws) {
  int idx = blockIdx.x * 256 + threadIdx.x;
  if (idx < 49152) {
    int j = idx / 128, k = idx % 128;            // w_ih/w_hh are (384,128) row-major
    ws[OFF_WIHT + k * 384 + j] = w_ih[idx];
    ws[OFF_WHHT + k * 384 + j] = w_hh[idx];
    int i = idx / 384, jj = idx % 384;           // W_read is (128,384) row-major
    ws[OFF_WREADT + jj * 128 + i] = W_read[idx];
  }
  if (idx < 16384) {
    int j = idx / 128, k = idx % 128;            // W_in/W_out (128,128)
    ws[OFF_WINT  + k * 128 + j] = W_in[idx];
    ws[OFF_WOUTT + k * 128 + j] = W_out[idx];
  }
}

// ------------------------------------------------------------------
// K1: per-sample dedup + edges + deg.  grid=512, block=128
__global__ void k_build(const int* __restrict__ x, int* __restrict__ nodes,
                        float* __restrict__ deg, int* __restrict__ esrc,
                        int* __restrict__ edst, int* __restrict__ info) {
  int b = blockIdx.x, tid = threadIdx.x;
  __shared__ int sseq[SEQL];
  __shared__ int sfo[SEQL];
  __shared__ unsigned char sisf[SEQL];
  __shared__ int srank[SEQL];
  __shared__ int spos[SEQL];
  __shared__ int scinv[SEQL];
  __shared__ float sdeg[SEQL];
  __shared__ int s_nn, s_cnt;

  if (tid < SEQL) sseq[tid] = x[b * SEQL + tid];
  __syncthreads();
  int t = (tid < SEQL) ? sseq[tid] : 0;
  bool valid = (tid < SEQL) && (t != 0);
  int f = tid;
  if (valid) {
    for (int j = 0; j < tid; ++j) {
      if (sseq[j] == t) { f = j; break; }
    }
  }
  if (tid < SEQL) {
    sfo[tid] = f;
    sisf[tid] = (valid && f == tid) ? 1 : 0;
    sdeg[tid] = 0.f;
  }
  __syncthreads();
  if (tid == 0) {
    int nn = 0, c = 0;
    for (int i = 0; i < SEQL; ++i) {
      srank[i] = nn; nn += sisf[i];
      spos[i] = c;  c += (sseq[i] != 0) ? 1 : 0;
    }
    s_nn = nn; s_cnt = c;
  }
  __syncthreads();
  int nn = s_nn, cnt = s_cnt;
  if (valid) scinv[spos[tid]] = srank[sfo[tid]];
  __syncthreads();
  if (tid < SEQL) {
    if (sisf[tid]) nodes[b * SEQL + srank[tid]] = t;
    if (tid >= nn) nodes[b * SEQL + tid] = 0;     // pad -> emb[0]==0
  }
  __syncthreads();
  if (tid == 0) {
    int ec = (cnt >= 2) ? cnt - 1 : 0;
    for (int e = 0; e < ec; ++e) {
      int s = scinv[e], dnode = scinv[e + 1];
      esrc[b * 99 + e] = s;
      edst[b * 99 + e] = dnode;
      sdeg[dnode] += 1.f;
    }
    info[b * 4 + 0] = ec;
    info[b * 4 + 1] = (cnt >= 1) ? scinv[cnt - 1] : 0;
    info[b * 4 + 2] = (cnt >= 2) ? 1 : 0;
    info[b * 4 + 3] = nn;
  }
  __syncthreads();
  if (tid < SEQL) deg[b * SEQL + tid] = fmaxf(sdeg[tid], 1.f);
}

// ------------------------------------------------------------------
// K2: XIN = gather(emb) @ W_inT ; HOUT = gather(emb) @ W_outT
// grid=800 (64 rows each), block=256.  thread tile: 8 rows x 4 j, both outputs.
__global__ __launch_bounds__(256) void k_gemm_inout(
    const float* __restrict__ emb, const float* __restrict__ ws,
    const int* __restrict__ nodes, float* __restrict__ xin, float* __restrict__ hout) {
  __shared__ float Xs[64 * 128];
  int tid = threadIdx.x;
  int rowbase = blockIdx.x * 64;
  const float4* emb4 = (const float4*)emb;
  float4* Xs4 = (float4*)Xs;
  for (int e = tid; e < 64 * 32; e += 256) {
    int r = e >> 5, c4 = e & 31;
    int tok = nodes[rowbase + r];
    Xs4[e] = emb4[(size_t)tok * 32 + c4];
  }
  __syncthreads();
  int jt = tid & 31;   // j quad
  int rt = tid >> 5;   // row group of 8
  const float4* Wi4 = (const float4*)(ws + OFF_WINT);
  const float4* Wo4 = (const float4*)(ws + OFF_WOUTT);
  float accI[8][4]; float accO[8][4];
  #pragma unroll
  for (int r = 0; r < 8; ++r)
    #pragma unroll
    for (int j = 0; j < 4; ++j) { accI[r][j] = 0.f; accO[r][j] = 0.f; }

  for (int k0 = 0; k0 < 128; k0 += 4) {
    float wi[4][4], wo[4][4];
    #pragma unroll
    for (int kk = 0; kk < 4; ++kk) {
      float4 a = Wi4[(k0 + kk) * 32 + jt];
      wi[kk][0] = a.x; wi[kk][1] = a.y; wi[kk][2] = a.z; wi[kk][3] = a.w;
      float4 o = Wo4[(k0 + kk) * 32 + jt];
      wo[kk][0] = o.x; wo[kk][1] = o.y; wo[kk][2] = o.z; wo[kk][3] = o.w;
    }
    #pragma unroll
    for (int r = 0; r < 8; ++r) {
      float4 xv4 = Xs4[(rt * 8 + r) * 32 + (k0 >> 2)];
      float xv[4] = {xv4.x, xv4.y, xv4.z, xv4.w};
      #pragma unroll
      for (int kk = 0; kk < 4; ++kk)
        #pragma unroll
        for (int jj = 0; jj < 4; ++jj) {
          accI[r][jj] = fmaf(xv[kk], wi[kk][jj], accI[r][jj]);
          accO[r][jj] = fmaf(xv[kk], wo[kk][jj], accO[r][jj]);
        }
    }
  }
  float4* xin4 = (float4*)xin;
  float4* hout4 = (float4*)hout;
  #pragma unroll
  for (int r = 0; r < 8; ++r) {
    int row = rowbase + rt * 8 + r;
    float4 vI = {accI[r][0], accI[r][1], accI[r][2], accI[r][3]};
    float4 vO = {accO[r][0], accO[r][1], accO[r][2], accO[r][3]};
    xin4[(size_t)row * 32 + jt] = vI;
    hout4[(size_t)row * 32 + jt] = vO;
  }
}

// ------------------------------------------------------------------
// K3: XIN[dst] += HOUT[src]/deg[dst] per edge.  grid=512, block=128 (thread = k dim)
__global__ void k_scatter(const float* __restrict__ hout, float* __restrict__ xin,
                          const float* __restrict__ deg, const int* __restrict__ esrc,
                          const int* __restrict__ edst, const int* __restrict__ info) {
  int b = blockIdx.x, k = threadIdx.x;
  __shared__ float agg[SEQL * DIM];
  for (int n = 0; n < SEQL; ++n) agg[n * DIM + k] = 0.f;
  int ec = info[b * 4 + 0];
  for (int e = 0; e < ec; ++e) {
    int s = esrc[b * 99 + e], dn = edst[b * 99 + e];
    agg[dn * DIM + k] += hout[((size_t)(b * SEQL + s)) * DIM + k];
  }
  for (int n = 0; n < SEQL; ++n) {
    float dg = deg[b * SEQL + n];
    size_t idx = ((size_t)(b * SEQL + n)) * DIM + k;
    xin[idx] += agg[n * DIM + k] / dg;
  }
}

// ------------------------------------------------------------------
// K4: fused gi/gh GEMM + GRU gate.  grid=1600 (32 rows), block=256.
// thread tile: 4 rows x 4 j, three 128-col chunks (r,z,n) sequentially.
__global__ __launch_bounds__(256) void k_gru(
    const float* __restrict__ emb, const int* __restrict__ nodes,
    const float* __restrict__ ws, const float* __restrict__ xin,
    const float* __restrict__ b_ih, const float* __restrict__ b_hh,
    const int* __restrict__ info, float* __restrict__ Hbuf) {
  __shared__ float Xs[32 * 128];
  __shared__ float Hs[32 * 128];
  int tid = threadIdx.x;
  int rowbase = blockIdx.x * 32;
  const float4* emb4 = (const float4*)emb;
  float4* Xs4 = (float4*)Xs;
  float4* Hs4 = (float4*)Hs;
  const float4* xin4 = (const float4*)xin;
  for (int e = tid; e < 32 * 32; e += 256) {
    int r = e >> 5, c4 = e & 31;
    int row = rowbase + r;
    Xs4[e] = xin4[(size_t)row * 32 + c4];
    int tok = nodes[row];
    Hs4[e] = emb4[(size_t)tok * 32 + c4];
  }
  __syncthreads();
  int jt = tid & 31;   // j quad within chunk
  int rt = tid >> 5;   // row group of 4
  const float4* WiT4 = (const float4*)(ws + OFF_WIHT);
  const float4* WhT4 = (const float4*)(ws + OFF_WHHT);
  float Rreg[4][4], Zreg[4][4];

  for (int c = 0; c < 3; ++c) {
    float accI[4][4]; float accH[4][4];
    #pragma unroll
    for (int r = 0; r < 4; ++r)
      #pragma unroll
      for (int j = 0; j < 4; ++j) { accI[r][j] = 0.f; accH[r][j] = 0.f; }

    for (int k0 = 0; k0 < 128; k0 += 4) {
      float wi[4][4], wh[4][4];
      #pragma unroll
      for (int kk = 0; kk < 4; ++kk) {
        float4 a = WiT4[(k0 + kk) * 96 + c * 32 + jt];
        wi[kk][0] = a.x; wi[kk][1] = a.y; wi[kk][2] = a.z; wi[kk][3] = a.w;
        float4 h = WhT4[(k0 + kk) * 96 + c * 32 + jt];
        wh[kk][0] = h.x; wh[kk][1] = h.y; wh[kk][2] = h.z; wh[kk][3] = h.w;
      }
      #pragma unroll
      for (int r = 0; r < 4; ++r) {
        float4 xv4 = Xs4[(rt * 4 + r) * 32 + (k0 >> 2)];
        float4 hv4 = Hs4[(rt * 4 + r) * 32 + (k0 >> 2)];
        float xv[4] = {xv4.x, xv4.y, xv4.z, xv4.w};
        float hv[4] = {hv4.x, hv4.y, hv4.z, hv4.w};
        #pragma unroll
        for (int kk = 0; kk < 4; ++kk)
          #pragma unroll
          for (int jj = 0; jj < 4; ++jj) {
            accI[r][jj] = fmaf(xv[kk], wi[kk][jj], accI[r][jj]);
            accH[r][jj] = fmaf(hv[kk], wh[kk][jj], accH[r][jj]);
          }
      }
    }
    #pragma unroll
    for (int r = 0; r < 4; ++r) {
      int row = rowbase + rt * 4 + r;
      if (c < 2) {
        #pragma unroll
        for (int jj = 0; jj < 4; ++jj) {
          int j = jt * 4 + jj;
          float gi = accI[r][jj] + b_ih[c * 128 + j];
          float gh = accH[r][jj] + b_hh[c * 128 + j];
          float sg = 1.f / (1.f + expf(-(gi + gh)));
          if (c == 0) Rreg[r][jj] = sg; else Zreg[r][jj] = sg;
        }
      } else {
        float hval[4];
        #pragma unroll
        for (int jj = 0; jj < 4; ++jj) {
          int j = jt * 4 + jj;
          float gi = accI[r][jj] + b_ih[256 + j];
          float gh = accH[r][jj] + b_hh[256 + j];
          float nct = tanhf(gi + Rreg[r][jj] * gh);
          float h0 = Hs[(rt * 4 + r) * 128 + j];
          hval[jj] = (1.f - Zreg[r][jj]) * nct + Zreg[r][jj] * h0;
        }
        int bs = row / SEQL;
        int n = row - bs * SEQL;
        int nn = info[bs * 4 + 3];
        float4 v = {hval[0], hval[1], hval[2], hval[3]};
        if (n >= nn) { v.x = 0.f; v.y = 0.f; v.z = 0.f; v.w = 0.f; }
        ((float4*)Hbuf)[(size_t)row * 32 + jt] = v;
      }
    }
  }
}

// ------------------------------------------------------------------
// K5: attention + h_read.  grid=512, block=128
#define HLS 129
__global__ void k_attn(const float* __restrict__ Hbuf, const float* __restrict__ ws,
                       const float* __restrict__ b_read, const int* __restrict__ info,
                       float* __restrict__ hread) {
  int b = blockIdx.x, tid = threadIdx.x;
  __shared__ float Hl[SEQL * HLS];
  __shared__ float sc[128];
  __shared__ float hl[128];
  __shared__ float att[SEQL];
  __shared__ float loc[128];
  int nn = info[b * 4 + 3], li = info[b * 4 + 1];
  for (int e = tid; e < SEQL * 128; e += 128) {
    int r = e >> 7, k = e & 127;
    Hl[r * HLS + k] = Hbuf[((size_t)(b * SEQL + r)) * DIM + k];
  }
  __syncthreads();
  hl[tid] = Hl[li * HLS + tid];
  __syncthreads();
  float scr = NEGV;
  if (tid < nn) {
    float s = 0.f;
    for (int k = 0; k < 128; ++k) s += Hl[tid * HLS + k] * hl[k];
    scr = s;
  }
  sc[tid] = scr;
  __syncthreads();
  if (tid == 0) {
    float m = sc[0];
    for (int n = 1; n < SEQL; ++n) m = fmaxf(m, sc[n]);
    float sum = 0.f;
    for (int n = 0; n < SEQL; ++n) { float e = expf(sc[n] - m); att[n] = e; sum += e; }
    float inv = 1.f / sum;
    for (int n = 0; n < SEQL; ++n) att[n] *= inv;
  }
  __syncthreads();
  float lv = 0.f;
  for (int n = 0; n < SEQL; ++n) lv = fmaf(att[n], Hl[n * HLS + tid], lv);
  loc[tid] = lv;
  __syncthreads();
  const float* WrT = ws + OFF_WREADT;
  float acc = b_read[tid];
  for (int j = 0; j < 128; ++j) acc = fmaf(WrT[j * 128 + tid], hl[j], acc);
  for (int j = 0; j < 128; ++j) acc = fmaf(WrT[(128 + j) * 128 + tid], loc[j], acc);
  hread[b * 128 + tid] = tanhf(acc);
}

// ------------------------------------------------------------------
// K6: out = h_read @ emb^T (+ default rows).  grid=(49,64), block=256
// thread tile: 8 items x 8 batches
__global__ __launch_bounds__(256) void k_out(
    const float* __restrict__ emb, const float* __restrict__ hread,
    const int* __restrict__ info, float* __restrict__ out) {
  __shared__ float hs[8 * 128];
  int tid = threadIdx.x;
  int bb = blockIdx.y * 8;
  for (int e = tid; e < 8 * 128; e += 256) hs[e] = hread[bb * 128 + e];
  __syncthreads();
  int item0 = blockIdx.x * 2048 + tid;
  float acc[8][8];
  #pragma unroll
  for (int q = 0; q < 8; ++q)
    #pragma unroll
    for (int bt = 0; bt < 8; ++bt) acc[q][bt] = 0.f;

  const float4* emb4 = (const float4*)emb;
  const float4* hs4 = (const float4*)hs;
  for (int k0 = 0; k0 < 128; k0 += 4) {
    float hv[4][8];
    #pragma unroll
    for (int bt = 0; bt < 8; ++bt) {
      float4 h4 = hs4[bt * 32 + (k0 >> 2)];
      hv[0][bt] = h4.x; hv[1][bt] = h4.y; hv[2][bt] = h4.z; hv[3][bt] = h4.w;
    }
    #pragma unroll
    for (int q = 0; q < 8; ++q) {
      int it = item0 + q * 256;
      float4 e4 = {0.f, 0.f, 0.f, 0.f};
      if (it < NITEMS) e4 = emb4[(size_t)it * 32 + (k0 >> 2)];
      float ev[4] = {e4.x, e4.y, e4.z, e4.w};
      #pragma unroll
      for (int kk = 0; kk < 4; ++kk)
        #pragma unroll
        for (int bt = 0; bt < 8; ++bt)
          acc[q][bt] = fmaf(ev[kk], hv[kk][bt], acc[q][bt]);
    }
  }
  #pragma unroll
  for (int q = 0; q < 8; ++q) {
    int it = item0 + q * 256;
    if (it >= NITEMS) continue;
    #pragma unroll
    for (int bt = 0; bt < 8; ++bt) {
      int b = bb + bt;
      int flag = info[b * 4 + 2];
      float v = flag ? acc[q][bt] : ((it == 0) ? 0.f : NEGV);
      out[(size_t)b * NITEMS + it] = v;
    }
  }
}

// ------------------------------------------------------------------
extern "C" void kernel_launch(void* const* d_in, const int* in_sizes, int n_in,
                              void* d_out, int out_size, void* d_ws, size_t ws_size,
                              hipStream_t stream) {
  const int*   x      = (const int*)d_in[0];
  const float* emb    = (const float*)d_in[2];
  const float* W_in   = (const float*)d_in[3];
  const float* W_out  = (const float*)d_in[4];
  const float* w_ih   = (const float*)d_in[5];
  const float* w_hh   = (const float*)d_in[6];
  const float* b_ih   = (const float*)d_in[7];
  const float* b_hh   = (const float*)d_in[8];
  const float* W_read = (const float*)d_in[9];
  const float* b_read = (const float*)d_in[10];
  float* ws  = (float*)d_ws;
  int*   wsi = (int*)d_ws;
  float* out = (float*)d_out;

  k_prep<<<192, 256, 0, stream>>>(w_ih, w_hh, W_in, W_out, W_read, ws);
  k_build<<<BATCH, 128, 0, stream>>>(x, wsi + OFF_NODES_I, ws + OFF_DEG,
                                     wsi + OFF_SRC_I, wsi + OFF_DST_I, wsi + OFF_INFO_I);
  k_gemm_inout<<<800, 256, 0, stream>>>(emb, ws, wsi + OFF_NODES_I,
                                        ws + OFF_XIN, ws + OFF_HOUT);
  k_scatter<<<BATCH, 128, 0, stream>>>(ws + OFF_HOUT, ws + OFF_XIN, ws + OFF_DEG,
                                       wsi + OFF_SRC_I, wsi + OFF_DST_I, wsi + OFF_INFO_I);
  k_gru<<<1600, 256, 0, stream>>>(emb, wsi + OFF_NODES_I, ws, ws + OFF_XIN,
                                  b_ih, b_hh, wsi + OFF_INFO_I, ws + OFF_HOUT);
  k_attn<<<BATCH, 128, 0, stream>>>(ws + OFF_HOUT, ws, b_read, wsi + OFF_INFO_I,
                                    ws + OFF_HREAD);
  k_out<<<dim3(49, 64), 256, 0, stream>>>(emb, ws + OFF_HREAD, wsi + OFF_INFO_I, out);
}

// Round 2
// 754.787 us; speedup vs baseline: 4.9227x; 4.9227x over previous
//
#include <hip/hip_runtime.h>
#include <math.h>

#define BATCH 512
#define SEQL  100
#define DIM   128
#define NITEMS 100000
#define NEGV  -1000000000.0f

// ---- workspace layout (float offsets) ----
#define OFF_WIHT   0         // 128x384  [k*384+j]
#define OFF_WHHT   49152
#define OFF_WINT   98304     // 128x128  [k*128+j]
#define OFF_WOUTT  114688
#define OFF_WREADT 131072    // 384x128  [j*128+i]
#define OFF_HREAD  180224    // 512x128
#define OFF_DEG    245760    // 512x100
#define OFF_XIN    296960    // 51200x128
#define OFF_HOUT   6850560   // 51200x128 (later holds H)
// ---- int offsets (in ints from ws base) ----
#define OFF_NODES_I 13404160 // 512x100 tokens (padded with 0)
#define OFF_SRC_I   13455360 // 512x99
#define OFF_DST_I   13506048 // 512x99
#define OFF_INFO_I  13556736 // 512x4: ecnt, li, flag(cnt>=2), n_nodes

// ------------------------------------------------------------------
// K0: transpose weights into ws
__global__ void k_prep(const float* __restrict__ w_ih, const float* __restrict__ w_hh,
                       const float* __restrict__ W_in, const float* __restrict__ W_out,
                       const float* __restrict__ W_read, float* __restrict__ ws) {
  int idx = blockIdx.x * 256 + threadIdx.x;
  if (idx < 49152) {
    int j = idx / 128, k = idx % 128;            // w_ih/w_hh are (384,128) row-major
    ws[OFF_WIHT + k * 384 + j] = w_ih[idx];
    ws[OFF_WHHT + k * 384 + j] = w_hh[idx];
    int i = idx / 384, jj = idx % 384;           // W_read is (128,384) row-major
    ws[OFF_WREADT + jj * 128 + i] = W_read[idx];
  }
  if (idx < 16384) {
    int j = idx / 128, k = idx % 128;            // W_in/W_out (128,128)
    ws[OFF_WINT  + k * 128 + j] = W_in[idx];
    ws[OFF_WOUTT + k * 128 + j] = W_out[idx];
  }
}

// ------------------------------------------------------------------
// K1: per-sample dedup + edges + deg.  grid=512, block=128
__global__ void k_build(const int* __restrict__ x, int* __restrict__ nodes,
                        float* __restrict__ deg, int* __restrict__ esrc,
                        int* __restrict__ edst, int* __restrict__ info) {
  int b = blockIdx.x, tid = threadIdx.x;
  __shared__ int sseq[SEQL];
  __shared__ int sfo[SEQL];
  __shared__ unsigned char sisf[SEQL];
  __shared__ int srank[SEQL];
  __shared__ int spos[SEQL];
  __shared__ int scinv[SEQL];
  __shared__ float sdeg[SEQL];
  __shared__ int s_nn, s_cnt;

  if (tid < SEQL) sseq[tid] = x[b * SEQL + tid];
  __syncthreads();
  int t = (tid < SEQL) ? sseq[tid] : 0;
  bool valid = (tid < SEQL) && (t != 0);
  int f = tid;
  if (valid) {
    for (int j = 0; j < tid; ++j) {
      if (sseq[j] == t) { f = j; break; }
    }
  }
  if (tid < SEQL) {
    sfo[tid] = f;
    sisf[tid] = (valid && f == tid) ? 1 : 0;
    sdeg[tid] = 0.f;
  }
  __syncthreads();
  if (tid == 0) {
    int nn = 0, c = 0;
    for (int i = 0; i < SEQL; ++i) {
      srank[i] = nn; nn += sisf[i];
      spos[i] = c;  c += (sseq[i] != 0) ? 1 : 0;
    }
    s_nn = nn; s_cnt = c;
  }
  __syncthreads();
  int nn = s_nn, cnt = s_cnt;
  if (valid) scinv[spos[tid]] = srank[sfo[tid]];
  __syncthreads();
  if (tid < SEQL) {
    if (sisf[tid]) nodes[b * SEQL + srank[tid]] = t;
    if (tid >= nn) nodes[b * SEQL + tid] = 0;     // pad -> emb[0]==0
  }
  __syncthreads();
  if (tid == 0) {
    int ec = (cnt >= 2) ? cnt - 1 : 0;
    for (int e = 0; e < ec; ++e) {
      int s = scinv[e], dnode = scinv[e + 1];
      esrc[b * 99 + e] = s;
      edst[b * 99 + e] = dnode;
      sdeg[dnode] += 1.f;
    }
    info[b * 4 + 0] = ec;
    info[b * 4 + 1] = (cnt >= 1) ? scinv[cnt - 1] : 0;
    info[b * 4 + 2] = (cnt >= 2) ? 1 : 0;
    info[b * 4 + 3] = nn;
  }
  __syncthreads();
  if (tid < SEQL) deg[b * SEQL + tid] = fmaxf(sdeg[tid], 1.f);
}

// ------------------------------------------------------------------
// K2: XIN = gather(emb) @ W_inT ; HOUT = gather(emb) @ W_outT
// grid=800 (64 rows each), block=256.  thread tile: 8 rows x 4 j, both outputs.
__global__ __launch_bounds__(256) void k_gemm_inout(
    const float* __restrict__ emb, const float* __restrict__ ws,
    const int* __restrict__ nodes, float* __restrict__ xin, float* __restrict__ hout) {
  __shared__ float Xs[64 * 128];
  int tid = threadIdx.x;
  int rowbase = blockIdx.x * 64;
  const float4* emb4 = (const float4*)emb;
  float4* Xs4 = (float4*)Xs;
  for (int e = tid; e < 64 * 32; e += 256) {
    int r = e >> 5, c4 = e & 31;
    int tok = nodes[rowbase + r];
    Xs4[e] = emb4[(size_t)tok * 32 + c4];
  }
  __syncthreads();
  int jt = tid & 31;   // j quad
  int rt = tid >> 5;   // row group of 8
  const float4* Wi4 = (const float4*)(ws + OFF_WINT);
  const float4* Wo4 = (const float4*)(ws + OFF_WOUTT);
  float accI[8][4]; float accO[8][4];
  #pragma unroll
  for (int r = 0; r < 8; ++r)
    #pragma unroll
    for (int j = 0; j < 4; ++j) { accI[r][j] = 0.f; accO[r][j] = 0.f; }

  for (int k0 = 0; k0 < 128; k0 += 4) {
    float wi[4][4], wo[4][4];
    #pragma unroll
    for (int kk = 0; kk < 4; ++kk) {
      float4 a = Wi4[(k0 + kk) * 32 + jt];
      wi[kk][0] = a.x; wi[kk][1] = a.y; wi[kk][2] = a.z; wi[kk][3] = a.w;
      float4 o = Wo4[(k0 + kk) * 32 + jt];
      wo[kk][0] = o.x; wo[kk][1] = o.y; wo[kk][2] = o.z; wo[kk][3] = o.w;
    }
    #pragma unroll
    for (int r = 0; r < 8; ++r) {
      float4 xv4 = Xs4[(rt * 8 + r) * 32 + (k0 >> 2)];
      float xv[4] = {xv4.x, xv4.y, xv4.z, xv4.w};
      #pragma unroll
      for (int kk = 0; kk < 4; ++kk)
        #pragma unroll
        for (int jj = 0; jj < 4; ++jj) {
          accI[r][jj] = fmaf(xv[kk], wi[kk][jj], accI[r][jj]);
          accO[r][jj] = fmaf(xv[kk], wo[kk][jj], accO[r][jj]);
        }
    }
  }
  float4* xin4 = (float4*)xin;
  float4* hout4 = (float4*)hout;
  #pragma unroll
  for (int r = 0; r < 8; ++r) {
    int row = rowbase + rt * 8 + r;
    float4 vI = {accI[r][0], accI[r][1], accI[r][2], accI[r][3]};
    float4 vO = {accO[r][0], accO[r][1], accO[r][2], accO[r][3]};
    xin4[(size_t)row * 32 + jt] = vI;
    hout4[(size_t)row * 32 + jt] = vO;
  }
}

// ------------------------------------------------------------------
// K3: XIN[dst] += HOUT[src]/deg[dst] per edge.  grid=512, block=128 (thread = k dim)
__global__ void k_scatter(const float* __restrict__ hout, float* __restrict__ xin,
                          const float* __restrict__ deg, const int* __restrict__ esrc,
                          const int* __restrict__ edst, const int* __restrict__ info) {
  int b = blockIdx.x, k = threadIdx.x;
  __shared__ float agg[SEQL * DIM];
  for (int n = 0; n < SEQL; ++n) agg[n * DIM + k] = 0.f;
  int ec = info[b * 4 + 0];
  for (int e = 0; e < ec; ++e) {
    int s = esrc[b * 99 + e], dn = edst[b * 99 + e];
    agg[dn * DIM + k] += hout[((size_t)(b * SEQL + s)) * DIM + k];
  }
  for (int n = 0; n < SEQL; ++n) {
    float dg = deg[b * SEQL + n];
    size_t idx = ((size_t)(b * SEQL + n)) * DIM + k;
    xin[idx] += agg[n * DIM + k] / dg;
  }
}

// ------------------------------------------------------------------
// K4: fused gi/gh GEMM + GRU gate.  grid=1600 (32 rows), block=256.
// thread tile: 4 rows x 4 j, three 128-col chunks (r,z,n) sequentially.
__global__ __launch_bounds__(256) void k_gru(
    const float* __restrict__ emb, const int* __restrict__ nodes,
    const float* __restrict__ ws, const float* __restrict__ xin,
    const float* __restrict__ b_ih, const float* __restrict__ b_hh,
    const int* __restrict__ info, float* __restrict__ Hbuf) {
  __shared__ float Xs[32 * 128];
  __shared__ float Hs[32 * 128];
  int tid = threadIdx.x;
  int rowbase = blockIdx.x * 32;
  const float4* emb4 = (const float4*)emb;
  float4* Xs4 = (float4*)Xs;
  float4* Hs4 = (float4*)Hs;
  const float4* xin4 = (const float4*)xin;
  for (int e = tid; e < 32 * 32; e += 256) {
    int r = e >> 5, c4 = e & 31;
    int row = rowbase + r;
    Xs4[e] = xin4[(size_t)row * 32 + c4];
    int tok = nodes[row];
    Hs4[e] = emb4[(size_t)tok * 32 + c4];
  }
  __syncthreads();
  int jt = tid & 31;   // j quad within chunk
  int rt = tid >> 5;   // row group of 4
  const float4* WiT4 = (const float4*)(ws + OFF_WIHT);
  const float4* WhT4 = (const float4*)(ws + OFF_WHHT);
  float Rreg[4][4], Zreg[4][4];

  for (int c = 0; c < 3; ++c) {
    float accI[4][4]; float accH[4][4];
    #pragma unroll
    for (int r = 0; r < 4; ++r)
      #pragma unroll
      for (int j = 0; j < 4; ++j) { accI[r][j] = 0.f; accH[r][j] = 0.f; }

    for (int k0 = 0; k0 < 128; k0 += 4) {
      float wi[4][4], wh[4][4];
      #pragma unroll
      for (int kk = 0; kk < 4; ++kk) {
        float4 a = WiT4[(k0 + kk) * 96 + c * 32 + jt];
        wi[kk][0] = a.x; wi[kk][1] = a.y; wi[kk][2] = a.z; wi[kk][3] = a.w;
        float4 h = WhT4[(k0 + kk) * 96 + c * 32 + jt];
        wh[kk][0] = h.x; wh[kk][1] = h.y; wh[kk][2] = h.z; wh[kk][3] = h.w;
      }
      #pragma unroll
      for (int r = 0; r < 4; ++r) {
        float4 xv4 = Xs4[(rt * 4 + r) * 32 + (k0 >> 2)];
        float4 hv4 = Hs4[(rt * 4 + r) * 32 + (k0 >> 2)];
        float xv[4] = {xv4.x, xv4.y, xv4.z, xv4.w};
        float hv[4] = {hv4.x, hv4.y, hv4.z, hv4.w};
        #pragma unroll
        for (int kk = 0; kk < 4; ++kk)
          #pragma unroll
          for (int jj = 0; jj < 4; ++jj) {
            accI[r][jj] = fmaf(xv[kk], wi[kk][jj], accI[r][jj]);
            accH[r][jj] = fmaf(hv[kk], wh[kk][jj], accH[r][jj]);
          }
      }
    }
    #pragma unroll
    for (int r = 0; r < 4; ++r) {
      int row = rowbase + rt * 4 + r;
      if (c < 2) {
        #pragma unroll
        for (int jj = 0; jj < 4; ++jj) {
          int j = jt * 4 + jj;
          float gi = accI[r][jj] + b_ih[c * 128 + j];
          float gh = accH[r][jj] + b_hh[c * 128 + j];
          float sg = 1.f / (1.f + expf(-(gi + gh)));
          if (c == 0) Rreg[r][jj] = sg; else Zreg[r][jj] = sg;
        }
      } else {
        float hval[4];
        #pragma unroll
        for (int jj = 0; jj < 4; ++jj) {
          int j = jt * 4 + jj;
          float gi = accI[r][jj] + b_ih[256 + j];
          float gh = accH[r][jj] + b_hh[256 + j];
          float nct = tanhf(gi + Rreg[r][jj] * gh);
          float h0 = Hs[(rt * 4 + r) * 128 + j];
          hval[jj] = (1.f - Zreg[r][jj]) * nct + Zreg[r][jj] * h0;
        }
        int bs = row / SEQL;
        int n = row - bs * SEQL;
        int nn = info[bs * 4 + 3];
        float4 v = {hval[0], hval[1], hval[2], hval[3]};
        if (n >= nn) { v.x = 0.f; v.y = 0.f; v.z = 0.f; v.w = 0.f; }
        ((float4*)Hbuf)[(size_t)row * 32 + jt] = v;
      }
    }
  }
}

// ------------------------------------------------------------------
// K5: attention + h_read.  grid=512, block=128
#define HLS 129
__global__ void k_attn(const float* __restrict__ Hbuf, const float* __restrict__ ws,
                       const float* __restrict__ b_read, const int* __restrict__ info,
                       float* __restrict__ hread) {
  int b = blockIdx.x, tid = threadIdx.x;
  __shared__ float Hl[SEQL * HLS];
  __shared__ float sc[128];
  __shared__ float hl[128];
  __shared__ float att[SEQL];
  __shared__ float loc[128];
  int nn = info[b * 4 + 3], li = info[b * 4 + 1];
  for (int e = tid; e < SEQL * 128; e += 128) {
    int r = e >> 7, k = e & 127;
    Hl[r * HLS + k] = Hbuf[((size_t)(b * SEQL + r)) * DIM + k];
  }
  __syncthreads();
  hl[tid] = Hl[li * HLS + tid];
  __syncthreads();
  float scr = NEGV;
  if (tid < nn) {
    float s = 0.f;
    for (int k = 0; k < 128; ++k) s += Hl[tid * HLS + k] * hl[k];
    scr = s;
  }
  sc[tid] = scr;
  __syncthreads();
  if (tid == 0) {
    float m = sc[0];
    for (int n = 1; n < SEQL; ++n) m = fmaxf(m, sc[n]);
    float sum = 0.f;
    for (int n = 0; n < SEQL; ++n) { float e = expf(sc[n] - m); att[n] = e; sum += e; }
    float inv = 1.f / sum;
    for (int n = 0; n < SEQL; ++n) att[n] *= inv;
  }
  __syncthreads();
  float lv = 0.f;
  for (int n = 0; n < SEQL; ++n) lv = fmaf(att[n], Hl[n * HLS + tid], lv);
  loc[tid] = lv;
  __syncthreads();
  const float* WrT = ws + OFF_WREADT;
  float acc = b_read[tid];
  for (int j = 0; j < 128; ++j) acc = fmaf(WrT[j * 128 + tid], hl[j], acc);
  for (int j = 0; j < 128; ++j) acc = fmaf(WrT[(128 + j) * 128 + tid], loc[j], acc);
  hread[b * 128 + tid] = tanhf(acc);
}

// ------------------------------------------------------------------
// K6 v2: out = h_read @ emb^T as tiled GEMM.
// grid=(4, 782): x = batch tile of 128 (fast dim for L2/L3 emb-tile reuse),
// y = item tile of 128.  block=256, per-thread 8 batches x 8 items.
// K=128 streamed in chunks of 8 through LDS (k-major), register prefetch.
__global__ __launch_bounds__(256) void k_out(
    const float* __restrict__ emb, const float* __restrict__ hread,
    const int* __restrict__ info, float* __restrict__ out) {
  __shared__ float Es[8][132];   // [kk][item in tile]
  __shared__ float Hs[8][132];   // [kk][batch in tile]
  int tid = threadIdx.x;
  int b0  = blockIdx.x * 128;
  int it0 = blockIdx.y * 128;
  int ti = (tid & 15) * 8;       // item offset within tile (contiguous 8)
  int tb = (tid >> 4) * 8;       // batch offset within tile (contiguous 8)

  const float4* emb4 = (const float4*)emb;
  const float4* hr4  = (const float4*)hread;
  int li = tid >> 1;             // 0..127: row within tile for staging
  int lh = tid & 1;              // which float4 of the 8-wide k-chunk

  float acc[8][8];
  #pragma unroll
  for (int bt = 0; bt < 8; ++bt)
    #pragma unroll
    for (int q = 0; q < 8; ++q) acc[bt][q] = 0.f;

  // prefetch chunk 0
  int item = it0 + li;
  float4 e4 = {0.f, 0.f, 0.f, 0.f};
  if (item < NITEMS) e4 = emb4[(size_t)item * 32 + lh];
  float4 h4 = hr4[(size_t)(b0 + li) * 32 + lh];

  for (int k0 = 0; k0 < 128; k0 += 8) {
    __syncthreads();             // previous chunk's FMAs done
    Es[4 * lh + 0][li] = e4.x; Es[4 * lh + 1][li] = e4.y;
    Es[4 * lh + 2][li] = e4.z; Es[4 * lh + 3][li] = e4.w;
    Hs[4 * lh + 0][li] = h4.x; Hs[4 * lh + 1][li] = h4.y;
    Hs[4 * lh + 2][li] = h4.z; Hs[4 * lh + 3][li] = h4.w;
    __syncthreads();
    if (k0 + 8 < 128) {          // prefetch next chunk during FMAs
      int kq = ((k0 + 8) >> 2) + lh;
      e4 = (item < NITEMS) ? emb4[(size_t)item * 32 + kq]
                           : (float4){0.f, 0.f, 0.f, 0.f};
      h4 = hr4[(size_t)(b0 + li) * 32 + kq];
    }
    #pragma unroll
    for (int kk = 0; kk < 8; ++kk) {
      float4 ev0 = *(const float4*)&Es[kk][ti];
      float4 ev1 = *(const float4*)&Es[kk][ti + 4];
      float4 hv0 = *(const float4*)&Hs[kk][tb];
      float4 hv1 = *(const float4*)&Hs[kk][tb + 4];
      float ev[8] = {ev0.x, ev0.y, ev0.z, ev0.w, ev1.x, ev1.y, ev1.z, ev1.w};
      float hv[8] = {hv0.x, hv0.y, hv0.z, hv0.w, hv1.x, hv1.y, hv1.z, hv1.w};
      #pragma unroll
      for (int bt = 0; bt < 8; ++bt)
        #pragma unroll
        for (int q = 0; q < 8; ++q)
          acc[bt][q] = fmaf(hv[bt], ev[q], acc[bt][q]);
    }
  }

  #pragma unroll
  for (int bt = 0; bt < 8; ++bt) {
    int b = b0 + tb + bt;
    int flag = info[b * 4 + 2];
    int itb = it0 + ti;
    #pragma unroll
    for (int qs = 0; qs < 2; ++qs) {
      int it = itb + qs * 4;
      if (it >= NITEMS) continue;      // NITEMS % 8 == 0 so float4 is all-or-nothing
      float4 v;
      if (flag) {
        v.x = acc[bt][qs * 4 + 0]; v.y = acc[bt][qs * 4 + 1];
        v.z = acc[bt][qs * 4 + 2]; v.w = acc[bt][qs * 4 + 3];
      } else {
        v.x = (it == 0) ? 0.f : NEGV; v.y = NEGV; v.z = NEGV; v.w = NEGV;
      }
      *(float4*)&out[(size_t)b * NITEMS + it] = v;
    }
  }
}

// ------------------------------------------------------------------
extern "C" void kernel_launch(void* const* d_in, const int* in_sizes, int n_in,
                              void* d_out, int out_size, void* d_ws, size_t ws_size,
                              hipStream_t stream) {
  const int*   x      = (const int*)d_in[0];
  const float* emb    = (const float*)d_in[2];
  const float* W_in   = (const float*)d_in[3];
  const float* W_out  = (const float*)d_in[4];
  const float* w_ih   = (const float*)d_in[5];
  const float* w_hh   = (const float*)d_in[6];
  const float* b_ih   = (const float*)d_in[7];
  const float* b_hh   = (const float*)d_in[8];
  const float* W_read = (const float*)d_in[9];
  const float* b_read = (const float*)d_in[10];
  float* ws  = (float*)d_ws;
  int*   wsi = (int*)d_ws;
  float* out = (float*)d_out;

  k_prep<<<192, 256, 0, stream>>>(w_ih, w_hh, W_in, W_out, W_read, ws);
  k_build<<<BATCH, 128, 0, stream>>>(x, wsi + OFF_NODES_I, ws + OFF_DEG,
                                     wsi + OFF_SRC_I, wsi + OFF_DST_I, wsi + OFF_INFO_I);
  k_gemm_inout<<<800, 256, 0, stream>>>(emb, ws, wsi + OFF_NODES_I,
                                        ws + OFF_XIN, ws + OFF_HOUT);
  k_scatter<<<BATCH, 128, 0, stream>>>(ws + OFF_HOUT, ws + OFF_XIN, ws + OFF_DEG,
                                       wsi + OFF_SRC_I, wsi + OFF_DST_I, wsi + OFF_INFO_I);
  k_gru<<<1600, 256, 0, stream>>>(emb, wsi + OFF_NODES_I, ws, ws + OFF_XIN,
                                  b_ih, b_hh, wsi + OFF_INFO_I, ws + OFF_HOUT);
  k_attn<<<BATCH, 128, 0, stream>>>(ws + OFF_HOUT, ws, b_read, wsi + OFF_INFO_I,
                                    ws + OFF_HREAD);
  k_out<<<dim3(4, 782), 256, 0, stream>>>(emb, ws + OFF_HREAD, wsi + OFF_INFO_I, out);
}

// Round 3
// 556.055 us; speedup vs baseline: 6.6820x; 1.3574x over previous
//
#include <hip/hip_runtime.h>
#include <math.h>

#define BATCH 512
#define SEQL  100
#define DIM   128
#define NITEMS 100000
#define NEGV  -1000000000.0f

// ---- workspace layout (float offsets) ----
#define OFF_WINT   98304     // 128x128  [k*128+j]
#define OFF_WOUTT  114688
#define OFF_WREADT 131072    // 384x128  [j*128+i]
#define OFF_HREAD  180224    // 512x128
#define OFF_DEG    245760    // 512x100
#define OFF_XIN    296960    // 51200x128
#define OFF_HOUT   6850560   // 51200x128 (later holds H)
// ---- int offsets (in ints from ws base) ----
#define OFF_NODES_I 13404160 // 512x100 tokens (padded with 0)
#define OFF_SRC_I   13455360 // 512x99
#define OFF_DST_I   13506048 // 512x99
#define OFF_INFO_I  13556736 // 512x4: ecnt, li, flag(cnt>=2), n_nodes
// packed GRU weights (bf16 hi/lo MFMA fragments), float offset
#define OFF_WPACK_F 13558784 // 196608 halves = 98304 floats

typedef __attribute__((ext_vector_type(8))) short bf16x8;
typedef __attribute__((ext_vector_type(4))) float f32x4;

__device__ __forceinline__ unsigned short bf16_rne(float x) {
  unsigned int u = __float_as_uint(x);
  unsigned int r = u + 0x7FFFu + ((u >> 16) & 1u);
  return (unsigned short)(r >> 16);
}
__device__ __forceinline__ float bf16_to_f(unsigned short h) {
  return __uint_as_float(((unsigned int)h) << 16);
}

// ------------------------------------------------------------------
// K0: transpose weights into ws + pack w_ih/w_hh as bf16 hi/lo MFMA B-frags.
// wpack layout: [mat(2)][n_tile(24)][k_chunk(4)][hi/lo(2)][lane(64)][8 halves]
// B-frag content: lane(quad,n) holds W[n_tile*16+n][k_chunk*32+quad*8+j], j=0..7
__global__ void k_prep(const float* __restrict__ w_ih, const float* __restrict__ w_hh,
                       const float* __restrict__ W_in, const float* __restrict__ W_out,
                       const float* __restrict__ W_read, float* __restrict__ ws,
                       unsigned short* __restrict__ wpack) {
  int idx = blockIdx.x * 256 + threadIdx.x;
  if (idx < 98304) {
    int mat = idx / 49152, rem = idx % 49152;
    int n = rem / 128, k = rem % 128;
    float v = (mat ? w_hh : w_ih)[rem];          // (384,128) row-major
    unsigned short hi = bf16_rne(v);
    unsigned short lo = bf16_rne(v - bf16_to_f(hi));
    int nt = n >> 4, nn = n & 15, c = k >> 5, quad = (k >> 3) & 3, j = k & 7;
    int lane = quad * 16 + nn;
    size_t base = ((size_t)((mat * 24 + nt) * 4 + c)) * 1024 + (size_t)lane * 8 + j;
    wpack[base] = hi;
    wpack[base + 512] = lo;
  }
  if (idx < 49152) {
    int i = idx / 384, jj = idx % 384;           // W_read is (128,384) row-major
    ws[OFF_WREADT + jj * 128 + i] = W_read[idx];
  }
  if (idx < 16384) {
    int j = idx / 128, k = idx % 128;            // W_in/W_out (128,128)
    ws[OFF_WINT  + k * 128 + j] = W_in[idx];
    ws[OFF_WOUTT + k * 128 + j] = W_out[idx];
  }
}

// ------------------------------------------------------------------
// K1: per-sample dedup + edges + deg.  grid=512, block=128
__global__ void k_build(const int* __restrict__ x, int* __restrict__ nodes,
                        float* __restrict__ deg, int* __restrict__ esrc,
                        int* __restrict__ edst, int* __restrict__ info) {
  int b = blockIdx.x, tid = threadIdx.x;
  __shared__ int sseq[SEQL];
  __shared__ int sfo[SEQL];
  __shared__ unsigned char sisf[SEQL];
  __shared__ int srank[SEQL];
  __shared__ int spos[SEQL];
  __shared__ int scinv[SEQL];
  __shared__ float sdeg[SEQL];
  __shared__ int s_nn, s_cnt;

  if (tid < SEQL) sseq[tid] = x[b * SEQL + tid];
  __syncthreads();
  int t = (tid < SEQL) ? sseq[tid] : 0;
  bool valid = (tid < SEQL) && (t != 0);
  int f = tid;
  if (valid) {
    for (int j = 0; j < tid; ++j) {
      if (sseq[j] == t) { f = j; break; }
    }
  }
  if (tid < SEQL) {
    sfo[tid] = f;
    sisf[tid] = (valid && f == tid) ? 1 : 0;
    sdeg[tid] = 0.f;
  }
  __syncthreads();
  if (tid == 0) {
    int nn = 0, c = 0;
    for (int i = 0; i < SEQL; ++i) {
      srank[i] = nn; nn += sisf[i];
      spos[i] = c;  c += (sseq[i] != 0) ? 1 : 0;
    }
    s_nn = nn; s_cnt = c;
  }
  __syncthreads();
  int nn = s_nn, cnt = s_cnt;
  if (valid) scinv[spos[tid]] = srank[sfo[tid]];
  __syncthreads();
  if (tid < SEQL) {
    if (sisf[tid]) nodes[b * SEQL + srank[tid]] = t;
    if (tid >= nn) nodes[b * SEQL + tid] = 0;     // pad -> emb[0]==0
  }
  __syncthreads();
  if (tid == 0) {
    int ec = (cnt >= 2) ? cnt - 1 : 0;
    for (int e = 0; e < ec; ++e) {
      int s = scinv[e], dnode = scinv[e + 1];
      esrc[b * 99 + e] = s;
      edst[b * 99 + e] = dnode;
      sdeg[dnode] += 1.f;
    }
    info[b * 4 + 0] = ec;
    info[b * 4 + 1] = (cnt >= 1) ? scinv[cnt - 1] : 0;
    info[b * 4 + 2] = (cnt >= 2) ? 1 : 0;
    info[b * 4 + 3] = nn;
  }
  __syncthreads();
  if (tid < SEQL) deg[b * SEQL + tid] = fmaxf(sdeg[tid], 1.f);
}

// ------------------------------------------------------------------
// K2: XIN = gather(emb) @ W_inT ; HOUT = gather(emb) @ W_outT
__global__ __launch_bounds__(256) void k_gemm_inout(
    const float* __restrict__ emb, const float* __restrict__ ws,
    const int* __restrict__ nodes, float* __restrict__ xin, float* __restrict__ hout) {
  __shared__ float Xs[64 * 128];
  int tid = threadIdx.x;
  int rowbase = blockIdx.x * 64;
  const float4* emb4 = (const float4*)emb;
  float4* Xs4 = (float4*)Xs;
  for (int e = tid; e < 64 * 32; e += 256) {
    int r = e >> 5, c4 = e & 31;
    int tok = nodes[rowbase + r];
    Xs4[e] = emb4[(size_t)tok * 32 + c4];
  }
  __syncthreads();
  int jt = tid & 31;
  int rt = tid >> 5;
  const float4* Wi4 = (const float4*)(ws + OFF_WINT);
  const float4* Wo4 = (const float4*)(ws + OFF_WOUTT);
  float accI[8][4]; float accO[8][4];
  #pragma unroll
  for (int r = 0; r < 8; ++r)
    #pragma unroll
    for (int j = 0; j < 4; ++j) { accI[r][j] = 0.f; accO[r][j] = 0.f; }

  for (int k0 = 0; k0 < 128; k0 += 4) {
    float wi[4][4], wo[4][4];
    #pragma unroll
    for (int kk = 0; kk < 4; ++kk) {
      float4 a = Wi4[(k0 + kk) * 32 + jt];
      wi[kk][0] = a.x; wi[kk][1] = a.y; wi[kk][2] = a.z; wi[kk][3] = a.w;
      float4 o = Wo4[(k0 + kk) * 32 + jt];
      wo[kk][0] = o.x; wo[kk][1] = o.y; wo[kk][2] = o.z; wo[kk][3] = o.w;
    }
    #pragma unroll
    for (int r = 0; r < 8; ++r) {
      float4 xv4 = Xs4[(rt * 8 + r) * 32 + (k0 >> 2)];
      float xv[4] = {xv4.x, xv4.y, xv4.z, xv4.w};
      #pragma unroll
      for (int kk = 0; kk < 4; ++kk)
        #pragma unroll
        for (int jj = 0; jj < 4; ++jj) {
          accI[r][jj] = fmaf(xv[kk], wi[kk][jj], accI[r][jj]);
          accO[r][jj] = fmaf(xv[kk], wo[kk][jj], accO[r][jj]);
        }
    }
  }
  float4* xin4 = (float4*)xin;
  float4* hout4 = (float4*)hout;
  #pragma unroll
  for (int r = 0; r < 8; ++r) {
    int row = rowbase + rt * 8 + r;
    float4 vI = {accI[r][0], accI[r][1], accI[r][2], accI[r][3]};
    float4 vO = {accO[r][0], accO[r][1], accO[r][2], accO[r][3]};
    xin4[(size_t)row * 32 + jt] = vI;
    hout4[(size_t)row * 32 + jt] = vO;
  }
}

// ------------------------------------------------------------------
// K3: XIN[dst] += HOUT[src]/deg[dst] per edge.
__global__ void k_scatter(const float* __restrict__ hout, float* __restrict__ xin,
                          const float* __restrict__ deg, const int* __restrict__ esrc,
                          const int* __restrict__ edst, const int* __restrict__ info) {
  int b = blockIdx.x, k = threadIdx.x;
  __shared__ float agg[SEQL * DIM];
  for (int n = 0; n < SEQL; ++n) agg[n * DIM + k] = 0.f;
  int ec = info[b * 4 + 0];
  for (int e = 0; e < ec; ++e) {
    int s = esrc[b * 99 + e], dn = edst[b * 99 + e];
    agg[dn * DIM + k] += hout[((size_t)(b * SEQL + s)) * DIM + k];
  }
  for (int n = 0; n < SEQL; ++n) {
    float dg = deg[b * SEQL + n];
    size_t idx = ((size_t)(b * SEQL + n)) * DIM + k;
    xin[idx] += agg[n * DIM + k] / dg;
  }
}

// ------------------------------------------------------------------
// K4 v3: split-bf16 MFMA GRU.  grid=1600 (32 rows/block), block=128 (2 waves).
// Each wave: one 16-row m-tile, all 384 gi/gh cols via 16x16x32 MFMA,
// 3-term split (hi*hi + hi*lo + lo*hi) for ~fp32 accuracy.
#define GPAD 136
__global__ __launch_bounds__(128) void k_gru(
    const float* __restrict__ emb, const int* __restrict__ nodes,
    const unsigned short* __restrict__ wpack, const float* __restrict__ xin,
    const float* __restrict__ b_ih, const float* __restrict__ b_hh,
    const int* __restrict__ info, float* __restrict__ Hbuf) {
  __shared__ unsigned short Xhi[32 * GPAD];
  __shared__ unsigned short Xlo[32 * GPAD];
  __shared__ unsigned short Hhi[32 * GPAD];
  __shared__ unsigned short Hlo[32 * GPAD];
  int tid = threadIdx.x;
  int rowbase = blockIdx.x * 32;
  const float4* emb4 = (const float4*)emb;
  const float4* xin4 = (const float4*)xin;
  for (int e = tid; e < 32 * 32; e += 128) {
    int r = e >> 5, c4 = e & 31;
    int row = rowbase + r;
    float4 xv = xin4[(size_t)row * 32 + c4];
    int tok = nodes[row];
    float4 hv = emb4[(size_t)tok * 32 + c4];
    int base = r * GPAD + c4 * 4;
    float xs[4] = {xv.x, xv.y, xv.z, xv.w};
    float hs[4] = {hv.x, hv.y, hv.z, hv.w};
    #pragma unroll
    for (int q = 0; q < 4; ++q) {
      unsigned short xh = bf16_rne(xs[q]);
      Xhi[base + q] = xh; Xlo[base + q] = bf16_rne(xs[q] - bf16_to_f(xh));
      unsigned short hh = bf16_rne(hs[q]);
      Hhi[base + q] = hh; Hlo[base + q] = bf16_rne(hs[q] - bf16_to_f(hh));
    }
  }
  __syncthreads();
  int wave = tid >> 6, lane = tid & 63;
  int quad = lane >> 4, nIdx = lane & 15;
  int mrow = wave * 16 + nIdx;           // A-frag row (m = lane&15)
  bf16x8 aXh[4], aXl[4], aHh[4], aHl[4];
  #pragma unroll
  for (int c = 0; c < 4; ++c) {
    int off = mrow * GPAD + c * 32 + quad * 8;   // 16B-aligned (GPAD*2 % 16 == 0)
    aXh[c] = *(const bf16x8*)&Xhi[off];
    aXl[c] = *(const bf16x8*)&Xlo[off];
    aHh[c] = *(const bf16x8*)&Hhi[off];
    aHl[c] = *(const bf16x8*)&Hlo[off];
  }
  int grows[4]; int zm[4];
  #pragma unroll
  for (int i = 0; i < 4; ++i) {
    int grow = rowbase + wave * 16 + quad * 4 + i;
    grows[i] = grow;
    int bs = grow / SEQL;
    int n = grow - bs * SEQL;
    zm[i] = (n < info[bs * 4 + 3]) ? 1 : 0;
  }

  for (int t = 0; t < 8; ++t) {
    f32x4 acc[3][2];                     // [gate r/z/n][gi/gh]
    #pragma unroll
    for (int g = 0; g < 3; ++g)
      #pragma unroll
      for (int m = 0; m < 2; ++m) acc[g][m] = (f32x4){0.f, 0.f, 0.f, 0.f};

    for (int c = 0; c < 4; ++c) {
      bf16x8 Bh[3][2], Bl[3][2];
      #pragma unroll
      for (int g = 0; g < 3; ++g) {
        int nt = g * 8 + t;
        #pragma unroll
        for (int m = 0; m < 2; ++m) {
          size_t bidx = (size_t)((m * 24 + nt) * 4 + c) * 1024 + (size_t)lane * 8;
          Bh[g][m] = *(const bf16x8*)&wpack[bidx];
          Bl[g][m] = *(const bf16x8*)&wpack[bidx + 512];
        }
      }
      // split-major ordering: same acc touched every 6 MFMAs
      #pragma unroll
      for (int g = 0; g < 3; ++g) {
        acc[g][0] = __builtin_amdgcn_mfma_f32_16x16x32_bf16(aXh[c], Bh[g][0], acc[g][0], 0, 0, 0);
        acc[g][1] = __builtin_amdgcn_mfma_f32_16x16x32_bf16(aHh[c], Bh[g][1], acc[g][1], 0, 0, 0);
      }
      #pragma unroll
      for (int g = 0; g < 3; ++g) {
        acc[g][0] = __builtin_amdgcn_mfma_f32_16x16x32_bf16(aXh[c], Bl[g][0], acc[g][0], 0, 0, 0);
        acc[g][1] = __builtin_amdgcn_mfma_f32_16x16x32_bf16(aHh[c], Bl[g][1], acc[g][1], 0, 0, 0);
      }
      #pragma unroll
      for (int g = 0; g < 3; ++g) {
        acc[g][0] = __builtin_amdgcn_mfma_f32_16x16x32_bf16(aXl[c], Bh[g][0], acc[g][0], 0, 0, 0);
        acc[g][1] = __builtin_amdgcn_mfma_f32_16x16x32_bf16(aHl[c], Bh[g][1], acc[g][1], 0, 0, 0);
      }
    }
    int j = t * 16 + nIdx;
    float biR = b_ih[j],       bhR = b_hh[j];
    float biZ = b_ih[128 + j], bhZ = b_hh[128 + j];
    float biN = b_ih[256 + j], bhN = b_hh[256 + j];
    #pragma unroll
    for (int i = 0; i < 4; ++i) {
      float gr = acc[0][0][i] + biR + acc[0][1][i] + bhR;
      float gz = acc[1][0][i] + biZ + acc[1][1][i] + bhZ;
      float r = 1.f / (1.f + expf(-gr));
      float z = 1.f / (1.f + expf(-gz));
      float nct = tanhf(acc[2][0][i] + biN + r * (acc[2][1][i] + bhN));
      int lrow = wave * 16 + quad * 4 + i;
      float h0 = bf16_to_f(Hhi[lrow * GPAD + j]) + bf16_to_f(Hlo[lrow * GPAD + j]);
      float h = (1.f - z) * nct + z * h0;
      if (!zm[i]) h = 0.f;
      Hbuf[(size_t)grows[i] * 128 + j] = h;
    }
  }
}

// ------------------------------------------------------------------
// K5: attention + h_read.  grid=512, block=128
#define HLS 129
__global__ void k_attn(const float* __restrict__ Hbuf, const float* __restrict__ ws,
                       const float* __restrict__ b_read, const int* __restrict__ info,
                       float* __restrict__ hread) {
  int b = blockIdx.x, tid = threadIdx.x;
  __shared__ float Hl[SEQL * HLS];
  __shared__ float sc[128];
  __shared__ float hl[128];
  __shared__ float att[SEQL];
  __shared__ float loc[128];
  int nn = info[b * 4 + 3], li = info[b * 4 + 1];
  for (int e = tid; e < SEQL * 128; e += 128) {
    int r = e >> 7, k = e & 127;
    Hl[r * HLS + k] = Hbuf[((size_t)(b * SEQL + r)) * DIM + k];
  }
  __syncthreads();
  hl[tid] = Hl[li * HLS + tid];
  __syncthreads();
  float scr = NEGV;
  if (tid < nn) {
    float s = 0.f;
    for (int k = 0; k < 128; ++k) s += Hl[tid * HLS + k] * hl[k];
    scr = s;
  }
  sc[tid] = scr;
  __syncthreads();
  if (tid == 0) {
    float m = sc[0];
    for (int n = 1; n < SEQL; ++n) m = fmaxf(m, sc[n]);
    float sum = 0.f;
    for (int n = 0; n < SEQL; ++n) { float e = expf(sc[n] - m); att[n] = e; sum += e; }
    float inv = 1.f / sum;
    for (int n = 0; n < SEQL; ++n) att[n] *= inv;
  }
  __syncthreads();
  float lv = 0.f;
  for (int n = 0; n < SEQL; ++n) lv = fmaf(att[n], Hl[n * HLS + tid], lv);
  loc[tid] = lv;
  __syncthreads();
  const float* WrT = ws + OFF_WREADT;
  float acc = b_read[tid];
  for (int j = 0; j < 128; ++j) acc = fmaf(WrT[j * 128 + tid], hl[j], acc);
  for (int j = 0; j < 128; ++j) acc = fmaf(WrT[(128 + j) * 128 + tid], loc[j], acc);
  hread[b * 128 + tid] = tanhf(acc);
}

// ------------------------------------------------------------------
// K6 v2: out = h_read @ emb^T as tiled GEMM.
__global__ __launch_bounds__(256) void k_out(
    const float* __restrict__ emb, const float* __restrict__ hread,
    const int* __restrict__ info, float* __restrict__ out) {
  __shared__ float Es[8][132];   // [kk][item in tile]
  __shared__ float Hs[8][132];   // [kk][batch in tile]
  int tid = threadIdx.x;
  int b0  = blockIdx.x * 128;
  int it0 = blockIdx.y * 128;
  int ti = (tid & 15) * 8;
  int tb = (tid >> 4) * 8;

  const float4* emb4 = (const float4*)emb;
  const float4* hr4  = (const float4*)hread;
  int li = tid >> 1;
  int lh = tid & 1;

  float acc[8][8];
  #pragma unroll
  for (int bt = 0; bt < 8; ++bt)
    #pragma unroll
    for (int q = 0; q < 8; ++q) acc[bt][q] = 0.f;

  int item = it0 + li;
  float4 e4 = {0.f, 0.f, 0.f, 0.f};
  if (item < NITEMS) e4 = emb4[(size_t)item * 32 + lh];
  float4 h4 = hr4[(size_t)(b0 + li) * 32 + lh];

  for (int k0 = 0; k0 < 128; k0 += 8) {
    __syncthreads();
    Es[4 * lh + 0][li] = e4.x; Es[4 * lh + 1][li] = e4.y;
    Es[4 * lh + 2][li] = e4.z; Es[4 * lh + 3][li] = e4.w;
    Hs[4 * lh + 0][li] = h4.x; Hs[4 * lh + 1][li] = h4.y;
    Hs[4 * lh + 2][li] = h4.z; Hs[4 * lh + 3][li] = h4.w;
    __syncthreads();
    if (k0 + 8 < 128) {
      int kq = ((k0 + 8) >> 2) + lh;
      e4 = (item < NITEMS) ? emb4[(size_t)item * 32 + kq]
                           : (float4){0.f, 0.f, 0.f, 0.f};
      h4 = hr4[(size_t)(b0 + li) * 32 + kq];
    }
    #pragma unroll
    for (int kk = 0; kk < 8; ++kk) {
      float4 ev0 = *(const float4*)&Es[kk][ti];
      float4 ev1 = *(const float4*)&Es[kk][ti + 4];
      float4 hv0 = *(const float4*)&Hs[kk][tb];
      float4 hv1 = *(const float4*)&Hs[kk][tb + 4];
      float ev[8] = {ev0.x, ev0.y, ev0.z, ev0.w, ev1.x, ev1.y, ev1.z, ev1.w};
      float hv[8] = {hv0.x, hv0.y, hv0.z, hv0.w, hv1.x, hv1.y, hv1.z, hv1.w};
      #pragma unroll
      for (int bt = 0; bt < 8; ++bt)
        #pragma unroll
        for (int q = 0; q < 8; ++q)
          acc[bt][q] = fmaf(hv[bt], ev[q], acc[bt][q]);
    }
  }

  #pragma unroll
  for (int bt = 0; bt < 8; ++bt) {
    int b = b0 + tb + bt;
    int flag = info[b * 4 + 2];
    int itb = it0 + ti;
    #pragma unroll
    for (int qs = 0; qs < 2; ++qs) {
      int it = itb + qs * 4;
      if (it >= NITEMS) continue;
      float4 v;
      if (flag) {
        v.x = acc[bt][qs * 4 + 0]; v.y = acc[bt][qs * 4 + 1];
        v.z = acc[bt][qs * 4 + 2]; v.w = acc[bt][qs * 4 + 3];
      } else {
        v.x = (it == 0) ? 0.f : NEGV; v.y = NEGV; v.z = NEGV; v.w = NEGV;
      }
      *(float4*)&out[(size_t)b * NITEMS + it] = v;
    }
  }
}

// ------------------------------------------------------------------
extern "C" void kernel_launch(void* const* d_in, const int* in_sizes, int n_in,
                              void* d_out, int out_size, void* d_ws, size_t ws_size,
                              hipStream_t stream) {
  const int*   x      = (const int*)d_in[0];
  const float* emb    = (const float*)d_in[2];
  const float* W_in   = (const float*)d_in[3];
  const float* W_out  = (const float*)d_in[4];
  const float* w_ih   = (const float*)d_in[5];
  const float* w_hh   = (const float*)d_in[6];
  const float* b_ih   = (const float*)d_in[7];
  const float* b_hh   = (const float*)d_in[8];
  const float* W_read = (const float*)d_in[9];
  const float* b_read = (const float*)d_in[10];
  float* ws  = (float*)d_ws;
  int*   wsi = (int*)d_ws;
  unsigned short* wpack = (unsigned short*)(ws + OFF_WPACK_F);
  float* out = (float*)d_out;

  k_prep<<<384, 256, 0, stream>>>(w_ih, w_hh, W_in, W_out, W_read, ws, wpack);
  k_build<<<BATCH, 128, 0, stream>>>(x, wsi + OFF_NODES_I, ws + OFF_DEG,
                                     wsi + OFF_SRC_I, wsi + OFF_DST_I, wsi + OFF_INFO_I);
  k_gemm_inout<<<800, 256, 0, stream>>>(emb, ws, wsi + OFF_NODES_I,
                                        ws + OFF_XIN, ws + OFF_HOUT);
  k_scatter<<<BATCH, 128, 0, stream>>>(ws + OFF_HOUT, ws + OFF_XIN, ws + OFF_DEG,
                                       wsi + OFF_SRC_I, wsi + OFF_DST_I, wsi + OFF_INFO_I);
  k_gru<<<1600, 128, 0, stream>>>(emb, wsi + OFF_NODES_I, wpack, ws + OFF_XIN,
                                  b_ih, b_hh, wsi + OFF_INFO_I, ws + OFF_HOUT);
  k_attn<<<BATCH, 128, 0, stream>>>(ws + OFF_HOUT, ws, b_read, wsi + OFF_INFO_I,
                                    ws + OFF_HREAD);
  k_out<<<dim3(4, 782), 256, 0, stream>>>(emb, ws + OFF_HREAD, wsi + OFF_INFO_I, out);
}